// Round 11
// baseline (2325.851 us; speedup 1.0000x reference)
//
#include <hip/hip_runtime.h>
#include <math.h>

// Problem constants
constexpr int TT = 512;   // sequence length
constexpr int BB = 64;    // batch
constexpr int EE = 256;   // embed dim
constexpr int HH = 256;   // hidden
constexpr int SS = 64;    // states
constexpr int BH = BB * HH;         // 16384
constexpr int SLICE = 2048;         // floats per (t, sg) slice: 256 u x 8 s
constexpr int DIRSZ = TT * 8 * SLICE;  // floats per direction tensor (32 MB)

// ---------------------------------------------------------------------------
// embT2[t][sg][k][s] = embed[obs[t][b]][k],  b = sg*8 + s.
// ---------------------------------------------------------------------------
__global__ __launch_bounds__(256) void embT_prep(
    const int* __restrict__ obs, const float* __restrict__ embed,
    float* __restrict__ embT2)
{
    const int t   = blockIdx.x;
    const int tid = threadIdx.x;
    const int b   = tid & 63;
    const int kc  = tid >> 6;                       // 0..3
    const int tok = obs[t * BB + b];
    const float4* er = (const float4*)(embed + (size_t)tok * EE);
    float* dst = embT2 + ((size_t)t * 8 + (b >> 3)) * SLICE + (b & 7);
    #pragma unroll
    for (int i = 0; i < 16; ++i) {
        const int k4 = kc * 16 + i;
        float4 v = er[k4];
        const int k = k4 * 4;
        dst[(k + 0) * 8] = v.x;
        dst[(k + 1) * 8] = v.y;
        dst[(k + 2) * 8] = v.z;
        dst[(k + 3) * 8] = v.w;
    }
}

// ---------------------------------------------------------------------------
// Weight swizzle: WB[dir][ug][kc][k_l][r] = W[row][k]
//   row = (r>>4)*256 + ug*16 + (r&15),  k = kc*32 + k_l.
// Consumer wave kc, lane r loads 1 contiguous 256B line per k (L2-hot).
// ---------------------------------------------------------------------------
__global__ __launch_bounds__(256) void weight_prep(
    const float* __restrict__ Wih_f, const float* __restrict__ Whh_f,
    const float* __restrict__ Wih_b, const float* __restrict__ Whh_b,
    float* __restrict__ WBx, float* __restrict__ WBh)
{
    const int bx  = blockIdx.x;          // 256 = 2 dir x 16 ug x 8 kc
    const int dir = bx & 1;
    const int ug  = (bx >> 1) & 15;
    const int kc  = bx >> 5;             // 0..7
    const int tid = threadIdx.x;
    const float* Wih = dir ? Wih_b : Wih_f;
    const float* Whh = dir ? Whh_b : Whh_f;
    const size_t base = (((size_t)(dir * 16 + ug) * 8 + kc) * 32) * 64;
    #pragma unroll
    for (int i = 0; i < 8; ++i) {
        const int idx = tid + i * 256;   // 0..2047 = 32 k_l x 64 r
        const int kl  = idx >> 6;
        const int r   = idx & 63;
        const int row = (r >> 4) * 256 + ug * 16 + (r & 15);
        const int k   = kc * 32 + kl;
        WBx[base + (size_t)kl * 64 + r] = Wih[(size_t)row * EE + k];
        WBh[base + (size_t)kl * 64 + r] = Whh[(size_t)row * HH + k];
    }
}

// ---------------------------------------------------------------------------
// Persistent BiLSTM, 2D (sample-group x unit-group) partition.
// Grid 256 = 2 dir x 16 ug x 8 sg; 512 threads = 8 waves (wave = k-chunk kc,
// lane = local row r = gate*16 + u_local).
//
// R19 = R15 VERBATIM (the 1796us best: global weight loads both phases,
// bare __launch_bounds__(512) -> 60 VGPR, no spill) + ONE change:
//  * EARLY-ISSUED FIRST POLL ATTEMPT. R15 issued the first h-fetch only
//    after phase X, putting its ~700cy L3 round trip on the serial chain.
//    R19 issues the 4 h-loads BEFORE phase X (flight overlaps the x-dots),
//    then waits + NaN-checks after; on NaN it falls into the verbatim R15
//    retry loop. Ordering safety: the wait-asm carries "+v" on the four
//    h registers (true data dep -> check can't hoist past it, rule #18)
//    plus sched_barrier(0); compiler loads between issue and wait are
//    YOUNGER than ours, so compiler vmcnt(N) waits only over-wait.
// R18 lesson folded in: weight-register hoists are neutral-to-negative
// (loads already hidden under the wait) -> reverted to R15's global loads.
//
// Sync semantics unchanged (R8-proven): producer relaxed agent-scope
// atomic-exch stores; consumers poll the DATA with sc0 sc1 loads +
// NaN-sentinel check; bounded spins; NO plain loads on h (R14 lesson).
// Bit-exact: same ascending-k FMA order throughout.
// ---------------------------------------------------------------------------
__global__ __launch_bounds__(512) void lstm_grid(
    const float* __restrict__ embT2,
    const float* __restrict__ WBx, const float* __restrict__ WBh,
    const float* __restrict__ bih_f, const float* __restrict__ bhh_f,
    const float* __restrict__ bih_b, const float* __restrict__ bhh_b,
    const float* __restrict__ h0, const float* __restrict__ c0,
    float* __restrict__ HS2f, float* __restrict__ HS2b)
{
    __shared__ __align__(16) float xbuf[2][SLICE];  // 16 KB double-buffered x
    __shared__ __align__(16) float hbuf[SLICE];     // 8 KB h (intra-wave use)
    __shared__ float pb[8 * 520];                   // partials, padded stride

    const int tid = threadIdx.x;
    const int r   = tid & 63;       // local row: (r>>4)=gate, (r&15)=u_local
    const int kc  = tid >> 6;       // wave = k-chunk 0..7
    const int bx  = blockIdx.x;
    const int dir = bx & 1;
    const int ug  = (bx >> 1) & 15;
    const int sg  = bx >> 5;        // 0..7
    const int u0  = ug * 16;

    const float* bih = dir ? bih_b : bih_f;
    const float* bhh = dir ? bhh_b : bhh_f;
    float* HS = dir ? HS2b : HS2f;

    // per-thread weight bases (contiguous blob; k_l stride = 64 floats)
    const size_t wbase = (((size_t)(dir * 16 + ug) * 8 + kc) * 32) * 64 + r;
    const float* wx = WBx + wbase;
    const float* wh = WBh + wbase;

    // update-thread state (tid<128: uL = tid>>3, sU = tid&7)
    const int uL = tid >> 3;        // valid when tid<128
    const int sU = tid & 7;
    float c_reg = 0.0f;
    float bias0 = 0.f, bias1 = 0.f, bias2 = 0.f, bias3 = 0.f;
    if (tid < 128) {
        const int u  = u0 + uL;
        const int bg = sg * 8 + sU;
        c_reg = c0[dir * BH + bg * HH + u];
        bias0 = bih[0 * 256 + u] + bhh[0 * 256 + u];
        bias1 = bih[1 * 256 + u] + bhh[1 * 256 + u];
        bias2 = bih[2 * 256 + u] + bhh[2 * 256 + u];
        bias3 = bih[3 * 256 + u] + bhh[3 * 256 + u];
    }

    // ---- prologue: stage x(t0) and h0 (both intra-wave regions) ----
    {
        const int t0 = dir ? (TT - 1) : 0;
        const float4 xv = *(const float4*)(embT2
            + ((size_t)t0 * 8 + sg) * SLICE + (size_t)tid * 4);
        *(float4*)&xbuf[0][tid * 4] = xv;
        #pragma unroll
        for (int j = 0; j < 4; ++j) {
            const int idx = tid * 4 + j;          // = u*8 + s
            const int u = idx >> 3, s = idx & 7;
            hbuf[idx] = h0[dir * BH + (sg * 8 + s) * HH + u];
        }
    }
    __syncthreads();

    for (int step = 0; step < TT; ++step) {
        const int t   = dir ? (TT - 1 - step) : step;
        const int cur = step & 1;

        // ---- EARLY ISSUE: first h(t-1) fetch attempt, before phase X ----
        float h0v = 0.f, h1v = 0.f, h2v = 0.f, h3v = 0.f;
        if (step > 0) {
            const int tp = dir ? (t + 1) : (t - 1);
            const float* hsrc = HS + ((size_t)tp * 8 + sg) * SLICE
                                + kc * 256 + r;
            asm volatile(
                "global_load_dword %0, %4, off sc0 sc1\n\t"
                "global_load_dword %1, %4, off offset:256 sc0 sc1\n\t"
                "global_load_dword %2, %4, off offset:512 sc0 sc1\n\t"
                "global_load_dword %3, %4, off offset:768 sc0 sc1"
                : "=v"(h0v), "=v"(h1v), "=v"(h2v), "=v"(h3v)
                : "v"(hsrc)
                : "memory");
        }

        float acc0 = 0.f, acc1 = 0.f, acc2 = 0.f, acc3 = 0.f;
        float acc4 = 0.f, acc5 = 0.f, acc6 = 0.f, acc7 = 0.f;

        // ---- phase X: part += x[k][s]*Wx[row][k], k ascending ----
        {
            const float4* xb4 = (const float4*)&xbuf[cur][kc * 256];
            #pragma unroll 8
            for (int kl = 0; kl < 32; ++kl) {
                const float wv = wx[kl * 64];
                const float4 xa = xb4[kl * 2];
                const float4 xc = xb4[kl * 2 + 1];
                acc0 = fmaf(xa.x, wv, acc0); acc1 = fmaf(xa.y, wv, acc1);
                acc2 = fmaf(xa.z, wv, acc2); acc3 = fmaf(xa.w, wv, acc3);
                acc4 = fmaf(xc.x, wv, acc4); acc5 = fmaf(xc.y, wv, acc5);
                acc6 = fmaf(xc.z, wv, acc6); acc7 = fmaf(xc.w, wv, acc7);
            }
        }

        // ---- issue next step's x load (latency hides under the wait) ----
        const bool has_next = (step + 1 < TT);
        float4 xnext;
        if (has_next) {
            const int tn = dir ? (TT - 2 - step) : (step + 1);
            xnext = *(const float4*)(embT2
                + ((size_t)tn * 8 + sg) * SLICE + (size_t)tid * 4);
        }

        // ---- wait + verify early fetch; retry loop on sentinel (R15) ----
        if (step > 0) {
            const int tp = dir ? (t + 1) : (t - 1);
            const float* hsrc = HS + ((size_t)tp * 8 + sg) * SLICE
                                + kc * 256 + r;
            // data-dependent wait: "+v" ties the check to this asm (rule #18)
            asm volatile(
                "s_waitcnt vmcnt(0)"
                : "+v"(h0v), "+v"(h1v), "+v"(h2v), "+v"(h3v)
                :
                : "memory");
            __builtin_amdgcn_sched_barrier(0);
            const float ssum = (h0v + h1v) + (h2v + h3v);
            if (__any(ssum != ssum)) {
                // retry path: VERBATIM R15 poll loop
                int spins = 0;
                for (;;) {
                    asm volatile(
                        "global_load_dword %0, %4, off sc0 sc1\n\t"
                        "global_load_dword %1, %4, off offset:256 sc0 sc1\n\t"
                        "global_load_dword %2, %4, off offset:512 sc0 sc1\n\t"
                        "global_load_dword %3, %4, off offset:768 sc0 sc1\n\t"
                        "s_waitcnt vmcnt(0)"
                        : "=v"(h0v), "=v"(h1v), "=v"(h2v), "=v"(h3v)
                        : "v"(hsrc)
                        : "memory");
                    const float rsum = (h0v + h1v) + (h2v + h3v);
                    if (!__any(rsum != rsum)) break;
                    if (++spins > 200000) break;   // hard termination guarantee
                }
            }
            // redistribute to LDS (intra-wave region [kc*256, kc*256+256))
            const int hb = kc * 256 + r;
            hbuf[hb      ] = h0v;
            hbuf[hb +  64] = h1v;
            hbuf[hb + 128] = h2v;
            hbuf[hb + 192] = h3v;
        }

        // ---- stage next x into the other buffer (intra-wave region) ----
        if (has_next) *(float4*)&xbuf[cur ^ 1][tid * 4] = xnext;

        // ---- phase H: part += h[k][s]*Wh[row][k], k ascending ----
        {
            const float4* hb4 = (const float4*)&hbuf[kc * 256];
            #pragma unroll 8
            for (int kl = 0; kl < 32; ++kl) {
                const float wv = wh[kl * 64];
                const float4 ha = hb4[kl * 2];
                const float4 hc = hb4[kl * 2 + 1];
                acc0 = fmaf(ha.x, wv, acc0); acc1 = fmaf(ha.y, wv, acc1);
                acc2 = fmaf(ha.z, wv, acc2); acc3 = fmaf(ha.w, wv, acc3);
                acc4 = fmaf(hc.x, wv, acc4); acc5 = fmaf(hc.y, wv, acc5);
                acc6 = fmaf(hc.z, wv, acc6); acc7 = fmaf(hc.w, wv, acc7);
            }
        }

        // ---- publish partials: pb[s][kc*64 + r] ----
        {
            const int pbi = kc * 64 + r;
            pb[0 * 520 + pbi] = acc0; pb[1 * 520 + pbi] = acc1;
            pb[2 * 520 + pbi] = acc2; pb[3 * 520 + pbi] = acc3;
            pb[4 * 520 + pbi] = acc4; pb[5 * 520 + pbi] = acc5;
            pb[6 * 520 + pbi] = acc6; pb[7 * 520 + pbi] = acc7;
        }
        __syncthreads();   // the ONLY per-step block sync

        // ---- cell update (128 threads: u_local x sample) + h store ----
        if (tid < 128) {
            float p0 = bias0, p1 = bias1, p2 = bias2, p3 = bias3;
            #pragma unroll
            for (int q = 0; q < 8; ++q) {
                p0 += pb[sU * 520 + q * 64 + 0 * 16 + uL];
                p1 += pb[sU * 520 + q * 64 + 1 * 16 + uL];
                p2 += pb[sU * 520 + q * 64 + 2 * 16 + uL];
                p3 += pb[sU * 520 + q * 64 + 3 * 16 + uL];
            }
            const float ig = 1.0f / (1.0f + expf(-p0));
            const float fg = 1.0f / (1.0f + expf(-p1));
            const float gg = tanhf(p2);
            const float og = 1.0f / (1.0f + expf(-p3));
            c_reg = fg * c_reg + ig * gg;
            const float h = og * tanhf(c_reg);
            unsigned* dst = (unsigned*)(HS + ((size_t)t * 8 + sg) * SLICE
                                        + (u0 + uL) * 8 + sU);
            // atomic exchange at the L3 coherence point (R8-proven)
            (void)__hip_atomic_exchange(dst, __float_as_uint(h),
                                        __ATOMIC_RELAXED,
                                        __HIP_MEMORY_SCOPE_AGENT);
        }
    }
}

// ---------------------------------------------------------------------------
// scores[t,b,s] = sum_u hF[t][b][u]*W_lin[s][u] + hB[t][b][u]*W_lin[s][256+u]
//                 + b_lin[s].  One block per t. (A-stage adapted to HS2.)
// ---------------------------------------------------------------------------
__global__ __launch_bounds__(256) void scores_kernel(
    const float* __restrict__ HS2f, const float* __restrict__ HS2b,
    const float* __restrict__ W_lin, const float* __restrict__ b_lin,
    float* __restrict__ scores)
{
    __shared__ __align__(16) float As[128 * 64];   // As[u_l][b]
    __shared__ __align__(16) float Ws[128 * 64];   // Ws[u_l][s]
    const int t   = blockIdx.x;
    const int tid = threadIdx.x;
    const int bl  = tid & 63;
    const int kc  = tid >> 6;        // 0..3
    const int tb  = tid & 15;
    const int ts  = tid >> 4;

    float acc[4][4] = {};

    for (int chunk = 0; chunk < 4; ++chunk) {
        const int koff = chunk * 128;
        const float* srcH = (koff < 256) ? HS2f : HS2b;
        const int bu = koff & 255;
        #pragma unroll
        for (int i = 0; i < 8; ++i) {
            const int jg = tid + i * 256;          // 0..2047 = 8 sg x 256 j
            const int sg = jg >> 8;
            const int j  = jg & 255;
            const int kl = j >> 1;
            const int s0 = (j & 1) * 4;
            const float4 v = *(const float4*)(srcH
                + ((size_t)t * 8 + sg) * SLICE + (size_t)(bu + kl) * 8 + s0);
            *(float4*)&As[kl * 64 + sg * 8 + s0] = v;
        }
        const float4* wl4 = (const float4*)(W_lin + koff);  // row pitch 128 f4
        #pragma unroll
        for (int it = 0; it < 8; ++it) {
            const int k4 = it * 4 + kc;
            float4 wv = wl4[bl * 128 + k4];
            const int k = k4 * 4;
            Ws[(k + 0) * 64 + bl] = wv.x; Ws[(k + 1) * 64 + bl] = wv.y;
            Ws[(k + 2) * 64 + bl] = wv.z; Ws[(k + 3) * 64 + bl] = wv.w;
        }
        __syncthreads();
        #pragma unroll 4
        for (int k = 0; k < 128; ++k) {
            const float4 av = *(const float4*)&As[k * 64 + tb * 4];
            const float4 bv = *(const float4*)&Ws[k * 64 + ts * 4];
            acc[0][0] += av.x * bv.x; acc[0][1] += av.x * bv.y; acc[0][2] += av.x * bv.z; acc[0][3] += av.x * bv.w;
            acc[1][0] += av.y * bv.x; acc[1][1] += av.y * bv.y; acc[1][2] += av.y * bv.z; acc[1][3] += av.y * bv.w;
            acc[2][0] += av.z * bv.x; acc[2][1] += av.z * bv.y; acc[2][2] += av.z * bv.z; acc[2][3] += av.z * bv.w;
            acc[3][0] += av.w * bv.x; acc[3][1] += av.w * bv.y; acc[3][2] += av.w * bv.z; acc[3][3] += av.w * bv.w;
        }
        __syncthreads();
    }

    #pragma unroll
    for (int i = 0; i < 4; ++i) {
        const int bb = tb * 4 + i;
        #pragma unroll
        for (int j = 0; j < 4; ++j) {
            const int ss = ts * 4 + j;
            scores[(size_t)t * (BB * SS) + bb * SS + ss] = acc[i][j] + b_lin[ss];
        }
    }
}

// ---------------------------------------------------------------------------
// Viterbi forward + backtrace (unchanged).
// ---------------------------------------------------------------------------
__global__ __launch_bounds__(256) void viterbi_kernel(
    const float* __restrict__ scores, const float* __restrict__ pairwise,
    const float* __restrict__ start, const float* __restrict__ stop,
    float* __restrict__ out)
{
    __shared__ float delta[2][64];
    __shared__ float part[4][64];
    __shared__ int   pidx[4][64];
    __shared__ unsigned char bps[511 * 64];
    __shared__ float fin[64];

    const int b   = blockIdx.x;
    const int tid = threadIdx.x;
    const int s   = tid & 63;
    const int q   = tid >> 6;

    float pw[16];
    #pragma unroll
    for (int i = 0; i < 16; ++i)
        pw[i] = pairwise[(q * 16 + i) * 64 + s];

    if (q == 0) delta[0][s] = start[s] + scores[b * SS + s];
    __syncthreads();

    int cur = 0;
    for (int t = 1; t < TT; ++t) {
        float sc = 0.0f;
        if (q == 0) sc = scores[(size_t)t * (BB * SS) + b * SS + s];
        float best = -1e30f;
        int bp = q * 16;
        #pragma unroll
        for (int i = 0; i < 16; ++i) {
            const float v = delta[cur][q * 16 + i] + pw[i];   // broadcast read
            if (v > best) { best = v; bp = q * 16 + i; }
        }
        part[q][s] = best;
        pidx[q][s] = bp;
        __syncthreads();
        if (q == 0) {
            float m = part[0][s];
            int arg = pidx[0][s];
            #pragma unroll
            for (int qq = 1; qq < 4; ++qq) {
                const float v = part[qq][s];
                if (v > m) { m = v; arg = pidx[qq][s]; }
            }
            delta[cur ^ 1][s] = m + sc;
            bps[(t - 1) * 64 + s] = (unsigned char)arg;
        }
        cur ^= 1;
        __syncthreads();
    }

    if (q == 0) fin[s] = delta[cur][s] + stop[s];
    __syncthreads();

    if (tid == 0) {
        float m = fin[0];
        int arg = 0;
        for (int p = 1; p < 64; ++p)
            if (fin[p] > m) { m = fin[p]; arg = p; }
        out[b] = m;
        int st = arg;
        out[64 + 511 * 64 + b] = (float)st;
        for (int k = 510; k >= 0; --k) {
            st = bps[k * 64 + st];
            out[64 + k * 64 + b] = (float)st;
        }
    }
}

// ---------------------------------------------------------------------------
extern "C" void kernel_launch(void* const* d_in, const int* in_sizes, int n_in,
                              void* d_out, int out_size, void* d_ws, size_t ws_size,
                              hipStream_t stream)
{
    const int*   obs      = (const int*)d_in[0];
    const float* h0       = (const float*)d_in[1];
    const float* c0       = (const float*)d_in[2];
    const float* embed    = (const float*)d_in[3];
    const float* Wih_f    = (const float*)d_in[4];
    const float* Whh_f    = (const float*)d_in[5];
    const float* bih_f    = (const float*)d_in[6];
    const float* bhh_f    = (const float*)d_in[7];
    const float* Wih_b    = (const float*)d_in[8];
    const float* Whh_b    = (const float*)d_in[9];
    const float* bih_b    = (const float*)d_in[10];
    const float* bhh_b    = (const float*)d_in[11];
    const float* W_lin    = (const float*)d_in[12];
    const float* b_lin    = (const float*)d_in[13];
    const float* pairwise = (const float*)d_in[14];
    const float* start    = (const float*)d_in[15];
    const float* stop     = (const float*)d_in[16];
    (void)in_sizes; (void)n_in; (void)out_size; (void)ws_size;

    // ws layout (floats): embT2 | HS2f | HS2b | scores  (~104 MB, unchanged)
    float* ws     = (float*)d_ws;
    float* embT2  = ws;
    float* HS2f   = embT2 + (size_t)DIRSZ;
    float* HS2b   = HS2f + (size_t)DIRSZ;
    float* scores = HS2b + (size_t)DIRSZ;
    // weight blobs overlay the scores region (4 MB of 8 MB): live only
    // during lstm_grid; scores_kernel runs strictly after and overwrites.
    float* WBx = scores;
    float* WBh = scores + (size_t)2 * 16 * 8 * 32 * 64;   // +2 MB

    // sentinel-init HS2f+HS2b (contiguous, 64 MB): 0xFF bytes = float NaN
    hipMemsetAsync(HS2f, 0xFF, (size_t)2 * DIRSZ * sizeof(float), stream);
    embT_prep<<<512, 256, 0, stream>>>(obs, embed, embT2);
    weight_prep<<<256, 256, 0, stream>>>(Wih_f, Whh_f, Wih_b, Whh_b, WBx, WBh);
    lstm_grid<<<256, 512, 0, stream>>>(
        embT2, WBx, WBh, bih_f, bhh_f, bih_b, bhh_b, h0, c0, HS2f, HS2b);
    scores_kernel<<<512, 256, 0, stream>>>(HS2f, HS2b, W_lin, b_lin, scores);
    viterbi_kernel<<<64, 256, 0, stream>>>(scores, pairwise, start, stop, (float*)d_out);
}

// Round 12
// 1999.506 us; speedup vs baseline: 1.1632x; 1.1632x over previous
//
#include <hip/hip_runtime.h>
#include <math.h>

// Problem constants
constexpr int TT = 512;   // sequence length
constexpr int BB = 64;    // batch
constexpr int EE = 256;   // embed dim
constexpr int HH = 256;   // hidden
constexpr int SS = 64;    // states
constexpr int BH = BB * HH;         // 16384
constexpr int SLICE = 2048;         // floats per (t, sg) slice: 256 u x 8 s
constexpr int DIRSZ = TT * 8 * SLICE;  // floats per direction tensor (32 MB)

// ---------------------------------------------------------------------------
// embT2[t][sg][k][s] = embed[obs[t][b]][k],  b = sg*8 + s.
// ---------------------------------------------------------------------------
__global__ __launch_bounds__(256) void embT_prep(
    const int* __restrict__ obs, const float* __restrict__ embed,
    float* __restrict__ embT2)
{
    const int t   = blockIdx.x;
    const int tid = threadIdx.x;
    const int b   = tid & 63;
    const int kc  = tid >> 6;                       // 0..3
    const int tok = obs[t * BB + b];
    const float4* er = (const float4*)(embed + (size_t)tok * EE);
    float* dst = embT2 + ((size_t)t * 8 + (b >> 3)) * SLICE + (b & 7);
    #pragma unroll
    for (int i = 0; i < 16; ++i) {
        const int k4 = kc * 16 + i;
        float4 v = er[k4];
        const int k = k4 * 4;
        dst[(k + 0) * 8] = v.x;
        dst[(k + 1) * 8] = v.y;
        dst[(k + 2) * 8] = v.z;
        dst[(k + 3) * 8] = v.w;
    }
}

// ---------------------------------------------------------------------------
// Weight swizzle: WB[dir][ug][kc][k_l][r] = W[row][k]
//   row = (r>>4)*256 + ug*16 + (r&15),  k = kc*32 + k_l.
// Consumer wave kc, lane r loads 1 contiguous 256B line per k (L2-hot).
// ---------------------------------------------------------------------------
__global__ __launch_bounds__(256) void weight_prep(
    const float* __restrict__ Wih_f, const float* __restrict__ Whh_f,
    const float* __restrict__ Wih_b, const float* __restrict__ Whh_b,
    float* __restrict__ WBx, float* __restrict__ WBh)
{
    const int bx  = blockIdx.x;          // 256 = 2 dir x 16 ug x 8 kc
    const int dir = bx & 1;
    const int ug  = (bx >> 1) & 15;
    const int kc  = bx >> 5;             // 0..7
    const int tid = threadIdx.x;
    const float* Wih = dir ? Wih_b : Wih_f;
    const float* Whh = dir ? Whh_b : Whh_f;
    const size_t base = (((size_t)(dir * 16 + ug) * 8 + kc) * 32) * 64;
    #pragma unroll
    for (int i = 0; i < 8; ++i) {
        const int idx = tid + i * 256;   // 0..2047 = 32 k_l x 64 r
        const int kl  = idx >> 6;
        const int r   = idx & 63;
        const int row = (r >> 4) * 256 + ug * 16 + (r & 15);
        const int k   = kc * 32 + kl;
        WBx[base + (size_t)kl * 64 + r] = Wih[(size_t)row * EE + k];
        WBh[base + (size_t)kl * 64 + r] = Whh[(size_t)row * HH + k];
    }
}

// ---------------------------------------------------------------------------
// Persistent BiLSTM, 2D (sample-group x unit-group) partition.
// Grid 256 = 2 dir x 16 ug x 8 sg; 512 threads = 8 waves (wave = k-chunk kc,
// lane = local row r = gate*16 + u_local).
//
// R20 = R15 VERBATIM (the 1796us best) + ONE producer-side change:
//  * COHERENT PLAIN STORE instead of atomic-exchange. R15's h-store was 128
//    separate 4B atomic-exch RMWs into just 2 cache lines — serialized at
//    the L3 coherence point (~64 ops/line), plausibly the dominant
//    unexplained chain segment. A global_store_dword with sc0 sc1 is the
//    write-coherent encoding (writes through to L3 — the exact mirror of
//    the sc0sc1 poll loads) but is a pipelined store, not a serialized RMW.
//    No ordering among the 128 stores is required: the NaN-sentinel logic
//    tolerates partial visibility (unwritten location = NaN -> retry).
//  * R19's early-issued poll REVERTED (fired too early -> extra retries,
//    FETCH +80MB, +290us). R15's post-phaseX first attempt is well-timed.
// Falsified to date: poll BW (R10/11), x-load latency (R13), L2
// amortization (R14 NaN), weight-load latency (R16-R18), early detect (R19).
//
// Consumer sync semantics unchanged (R8-proven): poll the DATA with sc0 sc1
// loads + NaN-sentinel check; bounded spins; NO plain loads on h (R14).
// Bit-exact: same ascending-k FMA order, same store values.
// ---------------------------------------------------------------------------
__global__ __launch_bounds__(512) void lstm_grid(
    const float* __restrict__ embT2,
    const float* __restrict__ WBx, const float* __restrict__ WBh,
    const float* __restrict__ bih_f, const float* __restrict__ bhh_f,
    const float* __restrict__ bih_b, const float* __restrict__ bhh_b,
    const float* __restrict__ h0, const float* __restrict__ c0,
    float* __restrict__ HS2f, float* __restrict__ HS2b)
{
    __shared__ __align__(16) float xbuf[2][SLICE];  // 16 KB double-buffered x
    __shared__ __align__(16) float hbuf[SLICE];     // 8 KB h (intra-wave use)
    __shared__ float pb[8 * 520];                   // partials, padded stride

    const int tid = threadIdx.x;
    const int r   = tid & 63;       // local row: (r>>4)=gate, (r&15)=u_local
    const int kc  = tid >> 6;       // wave = k-chunk 0..7
    const int bx  = blockIdx.x;
    const int dir = bx & 1;
    const int ug  = (bx >> 1) & 15;
    const int sg  = bx >> 5;        // 0..7
    const int u0  = ug * 16;

    const float* bih = dir ? bih_b : bih_f;
    const float* bhh = dir ? bhh_b : bhh_f;
    float* HS = dir ? HS2b : HS2f;

    // per-thread weight bases (contiguous blob; k_l stride = 64 floats)
    const size_t wbase = (((size_t)(dir * 16 + ug) * 8 + kc) * 32) * 64 + r;
    const float* wx = WBx + wbase;
    const float* wh = WBh + wbase;

    // update-thread state (tid<128: uL = tid>>3, sU = tid&7)
    const int uL = tid >> 3;        // valid when tid<128
    const int sU = tid & 7;
    float c_reg = 0.0f;
    float bias0 = 0.f, bias1 = 0.f, bias2 = 0.f, bias3 = 0.f;
    if (tid < 128) {
        const int u  = u0 + uL;
        const int bg = sg * 8 + sU;
        c_reg = c0[dir * BH + bg * HH + u];
        bias0 = bih[0 * 256 + u] + bhh[0 * 256 + u];
        bias1 = bih[1 * 256 + u] + bhh[1 * 256 + u];
        bias2 = bih[2 * 256 + u] + bhh[2 * 256 + u];
        bias3 = bih[3 * 256 + u] + bhh[3 * 256 + u];
    }

    // ---- prologue: stage x(t0) and h0 (both intra-wave regions) ----
    {
        const int t0 = dir ? (TT - 1) : 0;
        const float4 xv = *(const float4*)(embT2
            + ((size_t)t0 * 8 + sg) * SLICE + (size_t)tid * 4);
        *(float4*)&xbuf[0][tid * 4] = xv;
        #pragma unroll
        for (int j = 0; j < 4; ++j) {
            const int idx = tid * 4 + j;          // = u*8 + s
            const int u = idx >> 3, s = idx & 7;
            hbuf[idx] = h0[dir * BH + (sg * 8 + s) * HH + u];
        }
    }
    __syncthreads();

    for (int step = 0; step < TT; ++step) {
        const int t   = dir ? (TT - 1 - step) : step;
        const int cur = step & 1;

        float acc0 = 0.f, acc1 = 0.f, acc2 = 0.f, acc3 = 0.f;
        float acc4 = 0.f, acc5 = 0.f, acc6 = 0.f, acc7 = 0.f;

        // ---- phase X: part += x[k][s]*Wx[row][k], k ascending ----
        {
            const float4* xb4 = (const float4*)&xbuf[cur][kc * 256];
            #pragma unroll 8
            for (int kl = 0; kl < 32; ++kl) {
                const float wv = wx[kl * 64];
                const float4 xa = xb4[kl * 2];
                const float4 xc = xb4[kl * 2 + 1];
                acc0 = fmaf(xa.x, wv, acc0); acc1 = fmaf(xa.y, wv, acc1);
                acc2 = fmaf(xa.z, wv, acc2); acc3 = fmaf(xa.w, wv, acc3);
                acc4 = fmaf(xc.x, wv, acc4); acc5 = fmaf(xc.y, wv, acc5);
                acc6 = fmaf(xc.z, wv, acc6); acc7 = fmaf(xc.w, wv, acc7);
            }
        }

        // ---- issue next step's x load (latency hides under the poll) ----
        const bool has_next = (step + 1 < TT);
        float4 xnext;
        if (has_next) {
            const int tn = dir ? (TT - 2 - step) : (step + 1);
            xnext = *(const float4*)(embT2
                + ((size_t)tn * 8 + sg) * SLICE + (size_t)tid * 4);
        }

        // ---- h(t-1): sc0sc1 poll-on-data (R8 semantics), 4 lines/wave ----
        if (step > 0) {
            const int tp = dir ? (t + 1) : (t - 1);
            const float* hsrc = HS + ((size_t)tp * 8 + sg) * SLICE
                                + kc * 256 + r;
            float h0v, h1v, h2v, h3v;
            int spins = 0;
            for (;;) {
                asm volatile(
                    "global_load_dword %0, %4, off sc0 sc1\n\t"
                    "global_load_dword %1, %4, off offset:256 sc0 sc1\n\t"
                    "global_load_dword %2, %4, off offset:512 sc0 sc1\n\t"
                    "global_load_dword %3, %4, off offset:768 sc0 sc1\n\t"
                    "s_waitcnt vmcnt(0)"
                    : "=v"(h0v), "=v"(h1v), "=v"(h2v), "=v"(h3v)
                    : "v"(hsrc)
                    : "memory");
                const float ssum = (h0v + h1v) + (h2v + h3v);
                if (!__any(ssum != ssum)) break;
                if (++spins > 200000) break;   // hard termination guarantee
            }
            // redistribute to LDS (intra-wave region [kc*256, kc*256+256))
            const int hb = kc * 256 + r;
            hbuf[hb      ] = h0v;
            hbuf[hb +  64] = h1v;
            hbuf[hb + 128] = h2v;
            hbuf[hb + 192] = h3v;
        }

        // ---- stage next x into the other buffer (intra-wave region) ----
        if (has_next) *(float4*)&xbuf[cur ^ 1][tid * 4] = xnext;

        // ---- phase H: part += h[k][s]*Wh[row][k], k ascending ----
        {
            const float4* hb4 = (const float4*)&hbuf[kc * 256];
            #pragma unroll 8
            for (int kl = 0; kl < 32; ++kl) {
                const float wv = wh[kl * 64];
                const float4 ha = hb4[kl * 2];
                const float4 hc = hb4[kl * 2 + 1];
                acc0 = fmaf(ha.x, wv, acc0); acc1 = fmaf(ha.y, wv, acc1);
                acc2 = fmaf(ha.z, wv, acc2); acc3 = fmaf(ha.w, wv, acc3);
                acc4 = fmaf(hc.x, wv, acc4); acc5 = fmaf(hc.y, wv, acc5);
                acc6 = fmaf(hc.z, wv, acc6); acc7 = fmaf(hc.w, wv, acc7);
            }
        }

        // ---- publish partials: pb[s][kc*64 + r] ----
        {
            const int pbi = kc * 64 + r;
            pb[0 * 520 + pbi] = acc0; pb[1 * 520 + pbi] = acc1;
            pb[2 * 520 + pbi] = acc2; pb[3 * 520 + pbi] = acc3;
            pb[4 * 520 + pbi] = acc4; pb[5 * 520 + pbi] = acc5;
            pb[6 * 520 + pbi] = acc6; pb[7 * 520 + pbi] = acc7;
        }
        __syncthreads();   // the ONLY per-step block sync

        // ---- cell update (128 threads: u_local x sample) + h store ----
        if (tid < 128) {
            float p0 = bias0, p1 = bias1, p2 = bias2, p3 = bias3;
            #pragma unroll
            for (int q = 0; q < 8; ++q) {
                p0 += pb[sU * 520 + q * 64 + 0 * 16 + uL];
                p1 += pb[sU * 520 + q * 64 + 1 * 16 + uL];
                p2 += pb[sU * 520 + q * 64 + 2 * 16 + uL];
                p3 += pb[sU * 520 + q * 64 + 3 * 16 + uL];
            }
            const float ig = 1.0f / (1.0f + expf(-p0));
            const float fg = 1.0f / (1.0f + expf(-p1));
            const float gg = tanhf(p2);
            const float og = 1.0f / (1.0f + expf(-p3));
            c_reg = fg * c_reg + ig * gg;
            const float h = og * tanhf(c_reg);
            float* dst = HS + ((size_t)t * 8 + sg) * SLICE + (u0 + uL) * 8 + sU;
            // coherent plain store: sc0 sc1 writes through to the L3
            // coherence point (mirror of the consumers' sc0sc1 poll loads);
            // pipelined, unlike the serialized atomic-RMW burst it replaces.
            asm volatile(
                "global_store_dword %0, %1, off sc0 sc1"
                :
                : "v"(dst), "v"(h)
                : "memory");
        }
    }
}

// ---------------------------------------------------------------------------
// scores[t,b,s] = sum_u hF[t][b][u]*W_lin[s][u] + hB[t][b][u]*W_lin[s][256+u]
//                 + b_lin[s].  One block per t. (A-stage adapted to HS2.)
// ---------------------------------------------------------------------------
__global__ __launch_bounds__(256) void scores_kernel(
    const float* __restrict__ HS2f, const float* __restrict__ HS2b,
    const float* __restrict__ W_lin, const float* __restrict__ b_lin,
    float* __restrict__ scores)
{
    __shared__ __align__(16) float As[128 * 64];   // As[u_l][b]
    __shared__ __align__(16) float Ws[128 * 64];   // Ws[u_l][s]
    const int t   = blockIdx.x;
    const int tid = threadIdx.x;
    const int bl  = tid & 63;
    const int kc  = tid >> 6;        // 0..3
    const int tb  = tid & 15;
    const int ts  = tid >> 4;

    float acc[4][4] = {};

    for (int chunk = 0; chunk < 4; ++chunk) {
        const int koff = chunk * 128;
        const float* srcH = (koff < 256) ? HS2f : HS2b;
        const int bu = koff & 255;
        #pragma unroll
        for (int i = 0; i < 8; ++i) {
            const int jg = tid + i * 256;          // 0..2047 = 8 sg x 256 j
            const int sg = jg >> 8;
            const int j  = jg & 255;
            const int kl = j >> 1;
            const int s0 = (j & 1) * 4;
            const float4 v = *(const float4*)(srcH
                + ((size_t)t * 8 + sg) * SLICE + (size_t)(bu + kl) * 8 + s0);
            *(float4*)&As[kl * 64 + sg * 8 + s0] = v;
        }
        const float4* wl4 = (const float4*)(W_lin + koff);  // row pitch 128 f4
        #pragma unroll
        for (int it = 0; it < 8; ++it) {
            const int k4 = it * 4 + kc;
            float4 wv = wl4[bl * 128 + k4];
            const int k = k4 * 4;
            Ws[(k + 0) * 64 + bl] = wv.x; Ws[(k + 1) * 64 + bl] = wv.y;
            Ws[(k + 2) * 64 + bl] = wv.z; Ws[(k + 3) * 64 + bl] = wv.w;
        }
        __syncthreads();
        #pragma unroll 4
        for (int k = 0; k < 128; ++k) {
            const float4 av = *(const float4*)&As[k * 64 + tb * 4];
            const float4 bv = *(const float4*)&Ws[k * 64 + ts * 4];
            acc[0][0] += av.x * bv.x; acc[0][1] += av.x * bv.y; acc[0][2] += av.x * bv.z; acc[0][3] += av.x * bv.w;
            acc[1][0] += av.y * bv.x; acc[1][1] += av.y * bv.y; acc[1][2] += av.y * bv.z; acc[1][3] += av.y * bv.w;
            acc[2][0] += av.z * bv.x; acc[2][1] += av.z * bv.y; acc[2][2] += av.z * bv.z; acc[2][3] += av.z * bv.w;
            acc[3][0] += av.w * bv.x; acc[3][1] += av.w * bv.y; acc[3][2] += av.w * bv.z; acc[3][3] += av.w * bv.w;
        }
        __syncthreads();
    }

    #pragma unroll
    for (int i = 0; i < 4; ++i) {
        const int bb = tb * 4 + i;
        #pragma unroll
        for (int j = 0; j < 4; ++j) {
            const int ss = ts * 4 + j;
            scores[(size_t)t * (BB * SS) + bb * SS + ss] = acc[i][j] + b_lin[ss];
        }
    }
}

// ---------------------------------------------------------------------------
// Viterbi forward + backtrace (unchanged).
// ---------------------------------------------------------------------------
__global__ __launch_bounds__(256) void viterbi_kernel(
    const float* __restrict__ scores, const float* __restrict__ pairwise,
    const float* __restrict__ start, const float* __restrict__ stop,
    float* __restrict__ out)
{
    __shared__ float delta[2][64];
    __shared__ float part[4][64];
    __shared__ int   pidx[4][64];
    __shared__ unsigned char bps[511 * 64];
    __shared__ float fin[64];

    const int b   = blockIdx.x;
    const int tid = threadIdx.x;
    const int s   = tid & 63;
    const int q   = tid >> 6;

    float pw[16];
    #pragma unroll
    for (int i = 0; i < 16; ++i)
        pw[i] = pairwise[(q * 16 + i) * 64 + s];

    if (q == 0) delta[0][s] = start[s] + scores[b * SS + s];
    __syncthreads();

    int cur = 0;
    for (int t = 1; t < TT; ++t) {
        float sc = 0.0f;
        if (q == 0) sc = scores[(size_t)t * (BB * SS) + b * SS + s];
        float best = -1e30f;
        int bp = q * 16;
        #pragma unroll
        for (int i = 0; i < 16; ++i) {
            const float v = delta[cur][q * 16 + i] + pw[i];   // broadcast read
            if (v > best) { best = v; bp = q * 16 + i; }
        }
        part[q][s] = best;
        pidx[q][s] = bp;
        __syncthreads();
        if (q == 0) {
            float m = part[0][s];
            int arg = pidx[0][s];
            #pragma unroll
            for (int qq = 1; qq < 4; ++qq) {
                const float v = part[qq][s];
                if (v > m) { m = v; arg = pidx[qq][s]; }
            }
            delta[cur ^ 1][s] = m + sc;
            bps[(t - 1) * 64 + s] = (unsigned char)arg;
        }
        cur ^= 1;
        __syncthreads();
    }

    if (q == 0) fin[s] = delta[cur][s] + stop[s];
    __syncthreads();

    if (tid == 0) {
        float m = fin[0];
        int arg = 0;
        for (int p = 1; p < 64; ++p)
            if (fin[p] > m) { m = fin[p]; arg = p; }
        out[b] = m;
        int st = arg;
        out[64 + 511 * 64 + b] = (float)st;
        for (int k = 510; k >= 0; --k) {
            st = bps[k * 64 + st];
            out[64 + k * 64 + b] = (float)st;
        }
    }
}

// ---------------------------------------------------------------------------
extern "C" void kernel_launch(void* const* d_in, const int* in_sizes, int n_in,
                              void* d_out, int out_size, void* d_ws, size_t ws_size,
                              hipStream_t stream)
{
    const int*   obs      = (const int*)d_in[0];
    const float* h0       = (const float*)d_in[1];
    const float* c0       = (const float*)d_in[2];
    const float* embed    = (const float*)d_in[3];
    const float* Wih_f    = (const float*)d_in[4];
    const float* Whh_f    = (const float*)d_in[5];
    const float* bih_f    = (const float*)d_in[6];
    const float* bhh_f    = (const float*)d_in[7];
    const float* Wih_b    = (const float*)d_in[8];
    const float* Whh_b    = (const float*)d_in[9];
    const float* bih_b    = (const float*)d_in[10];
    const float* bhh_b    = (const float*)d_in[11];
    const float* W_lin    = (const float*)d_in[12];
    const float* b_lin    = (const float*)d_in[13];
    const float* pairwise = (const float*)d_in[14];
    const float* start    = (const float*)d_in[15];
    const float* stop     = (const float*)d_in[16];
    (void)in_sizes; (void)n_in; (void)out_size; (void)ws_size;

    // ws layout (floats): embT2 | HS2f | HS2b | scores  (~104 MB, unchanged)
    float* ws     = (float*)d_ws;
    float* embT2  = ws;
    float* HS2f   = embT2 + (size_t)DIRSZ;
    float* HS2b   = HS2f + (size_t)DIRSZ;
    float* scores = HS2b + (size_t)DIRSZ;
    // weight blobs overlay the scores region (4 MB of 8 MB): live only
    // during lstm_grid; scores_kernel runs strictly after and overwrites.
    float* WBx = scores;
    float* WBh = scores + (size_t)2 * 16 * 8 * 32 * 64;   // +2 MB

    // sentinel-init HS2f+HS2b (contiguous, 64 MB): 0xFF bytes = float NaN
    hipMemsetAsync(HS2f, 0xFF, (size_t)2 * DIRSZ * sizeof(float), stream);
    embT_prep<<<512, 256, 0, stream>>>(obs, embed, embT2);
    weight_prep<<<256, 256, 0, stream>>>(Wih_f, Whh_f, Wih_b, Whh_b, WBx, WBh);
    lstm_grid<<<256, 512, 0, stream>>>(
        embT2, WBx, WBh, bih_f, bhh_f, bih_b, bhh_b, h0, c0, HS2f, HS2b);
    scores_kernel<<<512, 256, 0, stream>>>(HS2f, HS2b, W_lin, b_lin, scores);
    viterbi_kernel<<<64, 256, 0, stream>>>(scores, pairwise, start, stop, (float*)d_out);
}